// Round 5
// baseline (338.868 us; speedup 1.0000x reference)
//
#include <hip/hip_runtime.h>

#define NEG_SLOPE 0.2f
#define CAP 64  // bucket capacity per node; overflow handled exactly

using f32x4 = __attribute__((ext_vector_type(4))) float;
using bf16x8 = __attribute__((ext_vector_type(8))) short;

__device__ inline unsigned short bf16_rne(float f) {
    unsigned int u = __float_as_uint(f);
    return (unsigned short)((u + 0x7FFF + ((u >> 16) & 1)) >> 16);
}
__device__ inline float bf16_tof(unsigned short h) {
    return __uint_as_float(((unsigned int)h) << 16);
}
__device__ inline unsigned short f16_rne(float f) {
    _Float16 h = (_Float16)f;                 // v_cvt_f16_f32, RNE
    return __builtin_bit_cast(unsigned short, h);
}
__device__ inline float f16_lo(unsigned int u) {
    _Float16 h = __builtin_bit_cast(_Float16, (unsigned short)(u & 0xFFFFu));
    return (float)h;
}
__device__ inline float f16_hi(unsigned int u) {
    _Float16 h = __builtin_bit_cast(_Float16, (unsigned short)(u >> 16));
    return (float)h;
}

// ---------------------------------------------------------------------------
// prep: wprep (first 24 blocks) + init head=-1 / ovf_cnt=0 (rest).
// ---------------------------------------------------------------------------
__global__ void prep_kernel(const float* __restrict__ W0,
                            const float* __restrict__ W1,
                            const float* __restrict__ W2,
                            unsigned short* __restrict__ wf,
                            int* __restrict__ head, int* __restrict__ ovf_c,
                            int N) {
    if (blockIdx.x < 24) {
        int tid = blockIdx.x * 256 + threadIdx.x;
        if (tid >= 3 * 2048) return;
        int layer = tid >> 11;
        int rem = tid & 2047;
        int kstep = rem >> 9;
        int ct = (rem >> 6) & 7;
        int lane = rem & 63;
        const float* W = (layer == 0) ? W0 : (layer == 1) ? W1 : W2;
        unsigned short* hi = wf + (size_t)layer * 32768 +
                             ((size_t)(kstep * 8 + ct) * 64 + lane) * 8;
        unsigned short* lo = hi + 16384;
#pragma unroll
        for (int j = 0; j < 8; ++j) {
            int k = kstep * 32 + (lane >> 4) * 8 + j;
            int n = ct * 16 + (lane & 15);
            float f = W[k * 128 + n];
            unsigned short h = bf16_rne(f);
            hi[j] = h;
            lo[j] = bf16_rne(f - bf16_tof(h));
        }
    } else {
        int i = (blockIdx.x - 24) * 256 + threadIdx.x;
        if (i < N) head[i] = -1;
        if (i == N) *ovf_c = 0;
    }
}

// ---------------------------------------------------------------------------
// Adjacency build, pass 1: per-dst linked list (atomicExch + coalesced 8B
// stream). R3 post-mortem: bound by the 800k device-scope atomics (~40-50us
// floor), not the store pattern.
// ---------------------------------------------------------------------------
__global__ void build_kernel(const void* __restrict__ ei_raw, int E,
                             int* __restrict__ head,
                             int2* __restrict__ nextsrc) {
    const int* as32 = (const int*)ei_raw;
    const long long* as64 = (const long long*)ei_raw;
    bool is64 = true;
    for (int k = 0; k < 16; ++k) {
        long long v = as64[k];
        if (!(v >= 0 && v < 2147483648LL)) { is64 = false; }
    }
    int i = blockIdx.x * blockDim.x + threadIdx.x;
    if (i < E) {
        int s, d;
        if (is64) {
            s = (int)as64[i];
            d = (int)as64[(size_t)E + i];
        } else {
            s = as32[i];
            d = as32[(size_t)E + i];
        }
        int old = atomicExch(&head[d], i);
        nextsrc[i] = make_int2(old, s);
    }
}

// ---------------------------------------------------------------------------
// Adjacency build, pass 2: walk each node's list, emit compact bucket rows.
// ---------------------------------------------------------------------------
__global__ void convert_kernel(const int* __restrict__ head,
                               const int2* __restrict__ nextsrc,
                               int* __restrict__ cnt, int* __restrict__ bucket,
                               int* __restrict__ ovf_src,
                               int* __restrict__ ovf_dst,
                               int* __restrict__ ovf_cnt, int N) {
    int n = blockIdx.x * blockDim.x + threadIdx.x;
    if (n >= N) return;
    int idx = head[n];
    int deg = 0;
    int* bk = bucket + (size_t)n * CAP;
    while (idx >= 0) {
        int2 ns = nextsrc[idx];
        if (deg < CAP) {
            bk[deg] = ns.y;
        } else {
            int q = atomicAdd(ovf_cnt, 1);
            ovf_src[q] = ns.y;
            ovf_dst[q] = n;
        }
        ++deg;
        idx = ns.x;
    }
    cnt[n] = deg;
}

// ---------------------------------------------------------------------------
// Split-bf16 MFMA GEMM + fused alpha epilogue (R10 structure).
// F16OUT: h stored as fp16 (rel err 2^-11 vs bf16's 2^-8).
// ---------------------------------------------------------------------------
template <int H, bool F16OUT>
__global__ __launch_bounds__(256) void gemm_kernel(
    const float* __restrict__ X, const unsigned short* __restrict__ wf_hi,
    const unsigned short* __restrict__ wf_lo, const float* __restrict__ asrc,
    const float* __restrict__ adst, void* __restrict__ Hout,
    float* __restrict__ alpha_s, float* __restrict__ alpha_d, int N) {
    int t = threadIdx.x;
    int wv = t >> 6;
    int l = t & 63;
    int m = l & 15;
    int quad = l >> 4;
    int row0 = blockIdx.x * 64 + wv * 16;

    f32x4 acc[8];
#pragma unroll
    for (int ct = 0; ct < 8; ++ct) acc[ct] = (f32x4){0.f, 0.f, 0.f, 0.f};

    int arow = row0 + m;
    bool okA = arow < N;
    const float4* X4 = (const float4*)X;

    for (int kstep = 0; kstep < 4; ++kstep) {
        float4 a0 = make_float4(0.f, 0.f, 0.f, 0.f);
        float4 a1 = make_float4(0.f, 0.f, 0.f, 0.f);
        if (okA) {
            a0 = X4[(size_t)arow * 32 + kstep * 8 + quad * 2];
            a1 = X4[(size_t)arow * 32 + kstep * 8 + quad * 2 + 1];
        }
        float av8[8] = {a0.x, a0.y, a0.z, a0.w, a1.x, a1.y, a1.z, a1.w};
        bf16x8 ah, al;
#pragma unroll
        for (int j = 0; j < 8; ++j) {
            unsigned short h = bf16_rne(av8[j]);
            ah[j] = (short)h;
            al[j] = (short)bf16_rne(av8[j] - bf16_tof(h));
        }
#pragma unroll
        for (int ct = 0; ct < 8; ++ct) {
            size_t boff = ((size_t)(kstep * 8 + ct) * 64 + l) * 8;
            bf16x8 bh = *(const bf16x8*)(wf_hi + boff);
            bf16x8 bl = *(const bf16x8*)(wf_lo + boff);
            acc[ct] = __builtin_amdgcn_mfma_f32_16x16x32_bf16(ah, bh, acc[ct], 0, 0, 0);
            acc[ct] = __builtin_amdgcn_mfma_f32_16x16x32_bf16(al, bh, acc[ct], 0, 0, 0);
            acc[ct] = __builtin_amdgcn_mfma_f32_16x16x32_bf16(ah, bl, acc[ct], 0, 0, 0);
        }
    }

#pragma unroll
    for (int reg = 0; reg < 4; ++reg) {
        int row = row0 + quad * 4 + reg;
        if (row < N) {
            if (F16OUT) {
                unsigned short* hb = (unsigned short*)Hout;
#pragma unroll
                for (int ct = 0; ct < 8; ++ct)
                    hb[(size_t)row * 128 + ct * 16 + m] = f16_rne(acc[ct][reg]);
            } else {
                float* hf = (float*)Hout;
#pragma unroll
                for (int ct = 0; ct < 8; ++ct)
                    hf[(size_t)row * 128 + ct * 16 + m] = acc[ct][reg];
            }
        }
    }

    float av[8], dv[8];
#pragma unroll
    for (int ct = 0; ct < 8; ++ct) {
        av[ct] = asrc[ct * 16 + m];
        dv[ct] = adst[ct * 16 + m];
    }
#pragma unroll
    for (int reg = 0; reg < 4; ++reg) {
        int row = row0 + quad * 4 + reg;
        if (H == 4) {
            float ps[4], pd[4];
#pragma unroll
            for (int hh = 0; hh < 4; ++hh) {
                ps[hh] = acc[2 * hh][reg] * av[2 * hh] +
                         acc[2 * hh + 1][reg] * av[2 * hh + 1];
                pd[hh] = acc[2 * hh][reg] * dv[2 * hh] +
                         acc[2 * hh + 1][reg] * dv[2 * hh + 1];
            }
#pragma unroll
            for (int o = 1; o < 16; o <<= 1) {
#pragma unroll
                for (int hh = 0; hh < 4; ++hh) {
                    ps[hh] += __shfl_xor(ps[hh], o);
                    pd[hh] += __shfl_xor(pd[hh], o);
                }
            }
            if (m == 0 && row < N) {
#pragma unroll
                for (int hh = 0; hh < 4; ++hh) {
                    alpha_s[(size_t)row * 4 + hh] = ps[hh];
                    alpha_d[(size_t)row * 4 + hh] = pd[hh];
                }
            }
        } else {
            float ps = 0.f, pd = 0.f;
#pragma unroll
            for (int ct = 0; ct < 8; ++ct) {
                ps += acc[ct][reg] * av[ct];
                pd += acc[ct][reg] * dv[ct];
            }
#pragma unroll
            for (int o = 1; o < 16; o <<= 1) {
                ps += __shfl_xor(ps, o);
                pd += __shfl_xor(pd, o);
            }
            if (m == 0 && row < N) {
                alpha_s[row] = ps;
                alpha_d[row] = pd;
            }
        }
    }
}

// ---------------------------------------------------------------------------
// Gather helpers: single-pass unnormalized softmax (R4) + node-strip
// software pipeline (R5). Each half-wave owns S consecutive nodes with a
// double-buffered LDS stage; stage(i+1) is issued before compute(i) in the
// same fence region so staging latency hides under the FMA/load stream.
// ---------------------------------------------------------------------------
template <int H>
__device__ __forceinline__ void stage_node(
    int i, int n0, int N, int sub, int l,
    const int* __restrict__ cnt, const int* __restrict__ bucket,
    const float* __restrict__ as_, const float* __restrict__ ad_,
    int (&s_src)[4][2][32], float (&s_w)[4][2][32 * H],
    float (&dsum)[2][H], int (&ndeg)[2], int (&ntb)[2]) {
    int b = i & 1;
    int nn = n0 + i;
    if (nn >= N) { ndeg[b] = -1; ntb[b] = 0; return; }
    int deg = cnt[nn];
    ndeg[b] = deg;
    int tb = min(deg, CAP) + 1;
    ntb[b] = tb;
#pragma unroll
    for (int hh = 0; hh < H; ++hh) dsum[b][hh] = 0.f;
    int tb0 = min(tb, 32);
    if (l < tb0) {
        int src = (l == 0) ? nn : bucket[(size_t)nn * CAP + l - 1];
        s_src[sub][b][l] = src;
        float adv[H];
#pragma unroll
        for (int hh = 0; hh < H; ++hh) adv[hh] = ad_[(size_t)nn * H + hh];
        if (H == 4) {
            float4 a4 = ((const float4*)as_)[src];
            float sv4[4] = {a4.x, a4.y, a4.z, a4.w};
#pragma unroll
            for (int hh = 0; hh < 4; ++hh) {
                float s = sv4[hh] + adv[hh];
                s = (s > 0.f) ? s : NEG_SLOPE * s;
                s = fminf(s, 80.f);
                float p = __expf(s);
                s_w[sub][b][l * 4 + hh] = p;
                dsum[b][hh] += p;
            }
        } else {
            float s = as_[src] + adv[0];
            s = (s > 0.f) ? s : NEG_SLOPE * s;
            s = fminf(s, 80.f);
            float p = __expf(s);
            s_w[sub][b][l] = p;
            dsum[b][0] += p;
        }
    }
}

template <int H>
__device__ __forceinline__ void fma_batch(
    int cnt2, int sub, int b, int g, int c, int head_c,
    const uint4* __restrict__ hb4,
    const int (&s_src)[4][2][32], const float (&s_w)[4][2][32 * H],
    float (&a8)[8]) {
    int j = 0;
    for (; j + 8 <= cnt2; j += 8) {
        int ts[4];
        float ws[4];
        uint4 rv[4];
#pragma unroll
        for (int u = 0; u < 4; ++u) {
            int e = j + 2 * u + g;
            ts[u] = s_src[sub][b][e];
            ws[u] = s_w[sub][b][e * H + head_c];
        }
#pragma unroll
        for (int u = 0; u < 4; ++u) rv[u] = hb4[(size_t)ts[u] * 16 + c];
#pragma unroll
        for (int u = 0; u < 4; ++u) {
            a8[0] += ws[u] * f16_lo(rv[u].x);
            a8[1] += ws[u] * f16_hi(rv[u].x);
            a8[2] += ws[u] * f16_lo(rv[u].y);
            a8[3] += ws[u] * f16_hi(rv[u].y);
            a8[4] += ws[u] * f16_lo(rv[u].z);
            a8[5] += ws[u] * f16_hi(rv[u].z);
            a8[6] += ws[u] * f16_lo(rv[u].w);
            a8[7] += ws[u] * f16_hi(rv[u].w);
        }
    }
    for (; j < cnt2; j += 2) {
        int e = j + g;
        if (e < cnt2) {
            int sj = s_src[sub][b][e];
            float wj = s_w[sub][b][e * H + head_c];
            uint4 rv = hb4[(size_t)sj * 16 + c];
            a8[0] += wj * f16_lo(rv.x);
            a8[1] += wj * f16_hi(rv.x);
            a8[2] += wj * f16_lo(rv.y);
            a8[3] += wj * f16_hi(rv.y);
            a8[4] += wj * f16_lo(rv.z);
            a8[5] += wj * f16_hi(rv.z);
            a8[6] += wj * f16_lo(rv.w);
            a8[7] += wj * f16_hi(rv.w);
        }
    }
}

template <int H>
__device__ __forceinline__ void compute_node(
    int i, int n0, int N, int sub, int l, int g, int c, int head_c,
    const uint4* __restrict__ hb4, const int* __restrict__ bucket,
    const float* __restrict__ as_, const float* __restrict__ ad_,
    const int* __restrict__ ovf_src, const int* __restrict__ ovf_dst,
    const int* __restrict__ ovf_cnt, const float (&bv8)[8],
    float* __restrict__ out,
    int (&s_src)[4][2][32], float (&s_w)[4][2][32 * H],
    float (&dsum)[2][H], int (&ndeg)[2], int (&ntb)[2]) {
    int b = i & 1;
    int nn = n0 + i;
    if (nn >= N) return;
    int deg = ndeg[b];
    int tb = ntb[b];
    float a8[8];
#pragma unroll
    for (int k = 0; k < 8; ++k) a8[k] = 0.f;

    // batch 0 — complete for 99.99% of nodes (deg <= 31)
    fma_batch<H>(min(32, tb), sub, b, g, c, head_c, hb4, s_src, s_w, a8);

    // extra batches (deg in (31, CAP]) — rare; restage in place
    for (int base = 32; base < tb; base += 32) {
        __builtin_amdgcn_wave_barrier();
        int cnt2 = min(32, tb - base);
        if (l < cnt2) {
            int src = bucket[(size_t)nn * CAP + base + l - 1];
            s_src[sub][b][l] = src;
            float adv[H];
#pragma unroll
            for (int hh = 0; hh < H; ++hh) adv[hh] = ad_[(size_t)nn * H + hh];
            if (H == 4) {
                float4 a4 = ((const float4*)as_)[src];
                float sv4[4] = {a4.x, a4.y, a4.z, a4.w};
#pragma unroll
                for (int hh = 0; hh < 4; ++hh) {
                    float s = sv4[hh] + adv[hh];
                    s = (s > 0.f) ? s : NEG_SLOPE * s;
                    s = fminf(s, 80.f);
                    float p = __expf(s);
                    s_w[sub][b][l * 4 + hh] = p;
                    dsum[b][hh] += p;
                }
            } else {
                float s = as_[src] + adv[0];
                s = (s > 0.f) ? s : NEG_SLOPE * s;
                s = fminf(s, 80.f);
                float p = __expf(s);
                s_w[sub][b][l] = p;
                dsum[b][0] += p;
            }
        }
        __builtin_amdgcn_wave_barrier();
        fma_batch<H>(cnt2, sub, b, g, c, head_c, hb4, s_src, s_w, a8);
    }

    // denominator reduce (within 32-lane half-wave)
#pragma unroll
    for (int o = 16; o > 0; o >>= 1)
#pragma unroll
        for (int hh = 0; hh < H; ++hh)
            dsum[b][hh] += __shfl_xor(dsum[b][hh], o);

    // overflow edges (deg > CAP): exact, rare; dsum stays lane-uniform
    int onum = (deg > CAP) ? *ovf_cnt : 0;
    for (int e = 0; e < onum; ++e) {
        if (ovf_dst[e] == nn) {
            int src = ovf_src[e];
            float pv[H];
            float adv[H];
#pragma unroll
            for (int hh = 0; hh < H; ++hh) adv[hh] = ad_[(size_t)nn * H + hh];
            if (H == 4) {
                float4 a4 = ((const float4*)as_)[src];
                float sv4[4] = {a4.x, a4.y, a4.z, a4.w};
#pragma unroll
                for (int hh = 0; hh < 4; ++hh) {
                    float s = sv4[hh] + adv[hh];
                    s = (s > 0.f) ? s : NEG_SLOPE * s;
                    s = fminf(s, 80.f);
                    pv[hh] = __expf(s);
                    dsum[b][hh] += pv[hh];
                }
            } else {
                float s = as_[src] + adv[0];
                s = (s > 0.f) ? s : NEG_SLOPE * s;
                s = fminf(s, 80.f);
                pv[0] = __expf(s);
                dsum[b][0] += pv[0];
            }
            if (g == 0) {
                float wj = pv[head_c];
                uint4 rv = hb4[(size_t)src * 16 + c];
                a8[0] += wj * f16_lo(rv.x);
                a8[1] += wj * f16_hi(rv.x);
                a8[2] += wj * f16_lo(rv.y);
                a8[3] += wj * f16_hi(rv.y);
                a8[4] += wj * f16_lo(rv.z);
                a8[5] += wj * f16_hi(rv.z);
                a8[6] += wj * f16_lo(rv.w);
                a8[7] += wj * f16_hi(rv.w);
            }
        }
    }

#pragma unroll
    for (int k = 0; k < 8; ++k) a8[k] += __shfl_xor(a8[k], 16);
    if (g == 0) {
        float invc = 1.f / dsum[b][head_c];
        float4 o0, o1;
        o0.x = fmaxf(a8[0] * invc + bv8[0], 0.f);
        o0.y = fmaxf(a8[1] * invc + bv8[1], 0.f);
        o0.z = fmaxf(a8[2] * invc + bv8[2], 0.f);
        o0.w = fmaxf(a8[3] * invc + bv8[3], 0.f);
        o1.x = fmaxf(a8[4] * invc + bv8[4], 0.f);
        o1.y = fmaxf(a8[5] * invc + bv8[5], 0.f);
        o1.z = fmaxf(a8[6] * invc + bv8[6], 0.f);
        o1.w = fmaxf(a8[7] * invc + bv8[7], 0.f);
        ((float4*)out)[(size_t)nn * 32 + c * 2] = o0;
        ((float4*)out)[(size_t)nn * 32 + c * 2 + 1] = o1;
    }
}

template <int H>
__global__ __launch_bounds__(128) void gather_kernel(
    const void* __restrict__ hvp, const float* __restrict__ as_,
    const float* __restrict__ ad_, const int* __restrict__ cnt,
    const int* __restrict__ bucket, const int* __restrict__ ovf_src,
    const int* __restrict__ ovf_dst, const int* __restrict__ ovf_cnt,
    const float* __restrict__ bias, float* __restrict__ out, int N) {
    constexpr int S = 4;  // nodes per half-wave strip
    __shared__ int   s_src[4][2][32];
    __shared__ float s_w[4][2][32 * H];
    int t = threadIdx.x;
    int wv = t >> 6;
    int lane = t & 63;
    int hw = lane >> 5;
    int l = lane & 31;
    int sub = wv * 2 + hw;
    int g = l >> 4;
    int c = l & 15;
    const int head_c = (H == 1) ? 0 : (c >> 2);
    const uint4* __restrict__ hb4 = (const uint4*)hvp;

    int n0 = (blockIdx.x * 4 + sub) * S;
    if (n0 >= N) return;

    float bv8[8];
#pragma unroll
    for (int k = 0; k < 8; ++k) bv8[k] = bias[c * 8 + k];

    float dsum[2][H];
    int ndeg[2], ntb[2];

    stage_node<H>(0, n0, N, sub, l, cnt, bucket, as_, ad_,
                  s_src, s_w, dsum, ndeg, ntb);
#pragma unroll
    for (int i = 0; i < S; ++i) {
        __builtin_amdgcn_wave_barrier();  // fence: stage(i) writes before reads
        if (i + 1 < S)
            stage_node<H>(i + 1, n0, N, sub, l, cnt, bucket, as_, ad_,
                          s_src, s_w, dsum, ndeg, ntb);
        compute_node<H>(i, n0, N, sub, l, g, c, head_c, hb4, bucket, as_, ad_,
                        ovf_src, ovf_dst, ovf_cnt, bv8, out,
                        s_src, s_w, dsum, ndeg, ntb);
    }
}

// ---------------------------------------------------------------------------
extern "C" void kernel_launch(void* const* d_in, const int* in_sizes, int n_in,
                              void* d_out, int out_size, void* d_ws,
                              size_t ws_size, hipStream_t stream) {
    const float* x   = (const float*)d_in[0];
    const void*  ei  = d_in[1];
    const float* W0  = (const float*)d_in[2];
    const float* as0 = (const float*)d_in[3];
    const float* ad0 = (const float*)d_in[4];
    const float* b0  = (const float*)d_in[5];
    const float* W1  = (const float*)d_in[6];
    const float* as1 = (const float*)d_in[7];
    const float* ad1 = (const float*)d_in[8];
    const float* b1  = (const float*)d_in[9];
    const float* W2  = (const float*)d_in[10];
    const float* as2 = (const float*)d_in[11];
    const float* ad2 = (const float*)d_in[12];
    const float* b2  = (const float*)d_in[13];

    int N = in_sizes[0] / 128;
    int E = in_sizes[1] / 2;
    float* out = (float*)d_out;

    float* h       = (float*)d_ws;                       // N*128 f32-sized (used as fp16)
    int2* nextsrc  = (int2*)(h + (size_t)N * 128);       // E int2
    float* alpha_s = (float*)(nextsrc + E);              // N*4 (max H)
    float* alpha_d = alpha_s + (size_t)N * 4;            // N*4
    int*   cnt     = (int*)(alpha_d + (size_t)N * 4);    // N
    int*   head    = cnt + N;                            // N
    int*   ovf_c   = head + N;                           // 1
    int*   bucket  = ovf_c + 1;                          // N*CAP
    int*   ovf_src = bucket + (size_t)N * CAP;           // E
    int*   ovf_dst = ovf_src + E;                        // E
    unsigned short* wf = (unsigned short*)(ovf_dst + E); // 3*32768 ushort

    int eb = (E + 255) / 256;
    int nb = (N + 1 + 255) / 256;
    int gb = (N + 63) / 64;
    int wb = (N + 15) / 16;   // 4 subs x S=4 nodes per block

    prep_kernel<<<24 + nb, 256, 0, stream>>>(W0, W1, W2, wf, head, ovf_c, N);
    build_kernel<<<eb, 256, 0, stream>>>(ei, E, head, nextsrc);
    convert_kernel<<<nb, 256, 0, stream>>>(head, nextsrc, cnt, bucket,
                                           ovf_src, ovf_dst, ovf_c, N);

    // layer 0
    gemm_kernel<4, true><<<gb, 256, 0, stream>>>(x, wf, wf + 16384, as0, ad0,
                                                 h, alpha_s, alpha_d, N);
    gather_kernel<4><<<wb, 128, 0, stream>>>(h, alpha_s, alpha_d, cnt,
                                             bucket, ovf_src, ovf_dst,
                                             ovf_c, b0, out, N);

    // layer 1
    gemm_kernel<4, true><<<gb, 256, 0, stream>>>(out, wf + 32768, wf + 49152,
                                                 as1, ad1, h, alpha_s, alpha_d, N);
    gather_kernel<4><<<wb, 128, 0, stream>>>(h, alpha_s, alpha_d, cnt,
                                             bucket, ovf_src, ovf_dst,
                                             ovf_c, b1, out, N);

    // layer 2 (H=1) — fp16 h storage, fp32 accumulation
    gemm_kernel<1, true><<<gb, 256, 0, stream>>>(out, wf + 65536, wf + 81920,
                                                 as2, ad2, h, alpha_s, alpha_d, N);
    gather_kernel<1><<<wb, 128, 0, stream>>>(h, alpha_s, alpha_d, cnt,
                                             bucket, ovf_src, ovf_dst,
                                             ovf_c, b2, out, N);
}

// Round 6
// 324.299 us; speedup vs baseline: 1.0449x; 1.0449x over previous
//
#include <hip/hip_runtime.h>

#define NEG_SLOPE 0.2f
#define CAP 64  // bucket capacity per node; overflow handled exactly

using f32x4 = __attribute__((ext_vector_type(4))) float;
using bf16x8 = __attribute__((ext_vector_type(8))) short;

__device__ inline unsigned short bf16_rne(float f) {
    unsigned int u = __float_as_uint(f);
    return (unsigned short)((u + 0x7FFF + ((u >> 16) & 1)) >> 16);
}
__device__ inline float bf16_tof(unsigned short h) {
    return __uint_as_float(((unsigned int)h) << 16);
}
__device__ inline unsigned short f16_rne(float f) {
    _Float16 h = (_Float16)f;                 // v_cvt_f16_f32, RNE
    return __builtin_bit_cast(unsigned short, h);
}
__device__ inline float f16_lo(unsigned int u) {
    _Float16 h = __builtin_bit_cast(_Float16, (unsigned short)(u & 0xFFFFu));
    return (float)h;
}
__device__ inline float f16_hi(unsigned int u) {
    _Float16 h = __builtin_bit_cast(_Float16, (unsigned short)(u >> 16));
    return (float)h;
}
__device__ inline unsigned int f16_pack(float a, float b) {
    return (unsigned int)f16_rne(a) | ((unsigned int)f16_rne(b) << 16);
}

// ---------------------------------------------------------------------------
// prep: wprep (first 24 blocks) + init head=-1 / ovf_cnt=0 (rest).
// ---------------------------------------------------------------------------
__global__ void prep_kernel(const float* __restrict__ W0,
                            const float* __restrict__ W1,
                            const float* __restrict__ W2,
                            unsigned short* __restrict__ wf,
                            int* __restrict__ head, int* __restrict__ ovf_c,
                            int N) {
    if (blockIdx.x < 24) {
        int tid = blockIdx.x * 256 + threadIdx.x;
        if (tid >= 3 * 2048) return;
        int layer = tid >> 11;
        int rem = tid & 2047;
        int kstep = rem >> 9;
        int ct = (rem >> 6) & 7;
        int lane = rem & 63;
        const float* W = (layer == 0) ? W0 : (layer == 1) ? W1 : W2;
        unsigned short* hi = wf + (size_t)layer * 32768 +
                             ((size_t)(kstep * 8 + ct) * 64 + lane) * 8;
        unsigned short* lo = hi + 16384;
#pragma unroll
        for (int j = 0; j < 8; ++j) {
            int k = kstep * 32 + (lane >> 4) * 8 + j;
            int n = ct * 16 + (lane & 15);
            float f = W[k * 128 + n];
            unsigned short h = bf16_rne(f);
            hi[j] = h;
            lo[j] = bf16_rne(f - bf16_tof(h));
        }
    } else {
        int i = (blockIdx.x - 24) * 256 + threadIdx.x;
        if (i < N) head[i] = -1;
        if (i == N) *ovf_c = 0;
    }
}

// ---------------------------------------------------------------------------
// Adjacency build, pass 1: per-dst linked list (atomicExch + coalesced 8B
// stream). Bound by the 800k device-scope atomics (~40-50us floor).
// ---------------------------------------------------------------------------
__global__ void build_kernel(const void* __restrict__ ei_raw, int E,
                             int* __restrict__ head,
                             int2* __restrict__ nextsrc) {
    const int* as32 = (const int*)ei_raw;
    const long long* as64 = (const long long*)ei_raw;
    bool is64 = true;
    for (int k = 0; k < 16; ++k) {
        long long v = as64[k];
        if (!(v >= 0 && v < 2147483648LL)) { is64 = false; }
    }
    int i = blockIdx.x * blockDim.x + threadIdx.x;
    if (i < E) {
        int s, d;
        if (is64) {
            s = (int)as64[i];
            d = (int)as64[(size_t)E + i];
        } else {
            s = as32[i];
            d = as32[(size_t)E + i];
        }
        int old = atomicExch(&head[d], i);
        nextsrc[i] = make_int2(old, s);
    }
}

// ---------------------------------------------------------------------------
// Adjacency build, pass 2: walk each node's list, emit compact bucket rows.
// ---------------------------------------------------------------------------
__global__ void convert_kernel(const int* __restrict__ head,
                               const int2* __restrict__ nextsrc,
                               int* __restrict__ cnt, int* __restrict__ bucket,
                               int* __restrict__ ovf_src,
                               int* __restrict__ ovf_dst,
                               int* __restrict__ ovf_cnt, int N) {
    int n = blockIdx.x * blockDim.x + threadIdx.x;
    if (n >= N) return;
    int idx = head[n];
    int deg = 0;
    int* bk = bucket + (size_t)n * CAP;
    while (idx >= 0) {
        int2 ns = nextsrc[idx];
        if (deg < CAP) {
            bk[deg] = ns.y;
        } else {
            int q = atomicAdd(ovf_cnt, 1);
            ovf_src[q] = ns.y;
            ovf_dst[q] = n;
        }
        ++deg;
        idx = ns.x;
    }
    cnt[n] = deg;
}

// ---------------------------------------------------------------------------
// Split-bf16 MFMA GEMM + fused alpha epilogue.
// XF16: input activations stored fp16 (layers 1/2) — halves X fetch.
// h output always fp16.
// ---------------------------------------------------------------------------
template <int H, bool XF16>
__global__ __launch_bounds__(256) void gemm_kernel(
    const void* __restrict__ Xp, const unsigned short* __restrict__ wf_hi,
    const unsigned short* __restrict__ wf_lo, const float* __restrict__ asrc,
    const float* __restrict__ adst, void* __restrict__ Hout,
    float* __restrict__ alpha_s, float* __restrict__ alpha_d, int N) {
    int t = threadIdx.x;
    int wv = t >> 6;
    int l = t & 63;
    int m = l & 15;
    int quad = l >> 4;
    int row0 = blockIdx.x * 64 + wv * 16;

    f32x4 acc[8];
#pragma unroll
    for (int ct = 0; ct < 8; ++ct) acc[ct] = (f32x4){0.f, 0.f, 0.f, 0.f};

    int arow = row0 + m;
    bool okA = arow < N;

    for (int kstep = 0; kstep < 4; ++kstep) {
        float av8[8];
        if (XF16) {
            uint4 u = make_uint4(0u, 0u, 0u, 0u);
            if (okA)
                u = ((const uint4*)Xp)[(size_t)arow * 16 + kstep * 4 + quad];
            av8[0] = f16_lo(u.x); av8[1] = f16_hi(u.x);
            av8[2] = f16_lo(u.y); av8[3] = f16_hi(u.y);
            av8[4] = f16_lo(u.z); av8[5] = f16_hi(u.z);
            av8[6] = f16_lo(u.w); av8[7] = f16_hi(u.w);
        } else {
            float4 a0 = make_float4(0.f, 0.f, 0.f, 0.f);
            float4 a1 = make_float4(0.f, 0.f, 0.f, 0.f);
            const float4* X4 = (const float4*)Xp;
            if (okA) {
                a0 = X4[(size_t)arow * 32 + kstep * 8 + quad * 2];
                a1 = X4[(size_t)arow * 32 + kstep * 8 + quad * 2 + 1];
            }
            av8[0] = a0.x; av8[1] = a0.y; av8[2] = a0.z; av8[3] = a0.w;
            av8[4] = a1.x; av8[5] = a1.y; av8[6] = a1.z; av8[7] = a1.w;
        }
        bf16x8 ah, al;
#pragma unroll
        for (int j = 0; j < 8; ++j) {
            unsigned short h = bf16_rne(av8[j]);
            ah[j] = (short)h;
            al[j] = (short)bf16_rne(av8[j] - bf16_tof(h));
        }
#pragma unroll
        for (int ct = 0; ct < 8; ++ct) {
            size_t boff = ((size_t)(kstep * 8 + ct) * 64 + l) * 8;
            bf16x8 bh = *(const bf16x8*)(wf_hi + boff);
            bf16x8 bl = *(const bf16x8*)(wf_lo + boff);
            acc[ct] = __builtin_amdgcn_mfma_f32_16x16x32_bf16(ah, bh, acc[ct], 0, 0, 0);
            acc[ct] = __builtin_amdgcn_mfma_f32_16x16x32_bf16(al, bh, acc[ct], 0, 0, 0);
            acc[ct] = __builtin_amdgcn_mfma_f32_16x16x32_bf16(ah, bl, acc[ct], 0, 0, 0);
        }
    }

#pragma unroll
    for (int reg = 0; reg < 4; ++reg) {
        int row = row0 + quad * 4 + reg;
        if (row < N) {
            unsigned short* hb = (unsigned short*)Hout;
#pragma unroll
            for (int ct = 0; ct < 8; ++ct)
                hb[(size_t)row * 128 + ct * 16 + m] = f16_rne(acc[ct][reg]);
        }
    }

    float av[8], dv[8];
#pragma unroll
    for (int ct = 0; ct < 8; ++ct) {
        av[ct] = asrc[ct * 16 + m];
        dv[ct] = adst[ct * 16 + m];
    }
#pragma unroll
    for (int reg = 0; reg < 4; ++reg) {
        int row = row0 + quad * 4 + reg;
        if (H == 4) {
            float ps[4], pd[4];
#pragma unroll
            for (int hh = 0; hh < 4; ++hh) {
                ps[hh] = acc[2 * hh][reg] * av[2 * hh] +
                         acc[2 * hh + 1][reg] * av[2 * hh + 1];
                pd[hh] = acc[2 * hh][reg] * dv[2 * hh] +
                         acc[2 * hh + 1][reg] * dv[2 * hh + 1];
            }
#pragma unroll
            for (int o = 1; o < 16; o <<= 1) {
#pragma unroll
                for (int hh = 0; hh < 4; ++hh) {
                    ps[hh] += __shfl_xor(ps[hh], o);
                    pd[hh] += __shfl_xor(pd[hh], o);
                }
            }
            if (m == 0 && row < N) {
#pragma unroll
                for (int hh = 0; hh < 4; ++hh) {
                    alpha_s[(size_t)row * 4 + hh] = ps[hh];
                    alpha_d[(size_t)row * 4 + hh] = pd[hh];
                }
            }
        } else {
            float ps = 0.f, pd = 0.f;
#pragma unroll
            for (int ct = 0; ct < 8; ++ct) {
                ps += acc[ct][reg] * av[ct];
                pd += acc[ct][reg] * dv[ct];
            }
#pragma unroll
            for (int o = 1; o < 16; o <<= 1) {
                ps += __shfl_xor(ps, o);
                pd += __shfl_xor(pd, o);
            }
            if (m == 0 && row < N) {
                alpha_s[row] = ps;
                alpha_d[row] = pd;
            }
        }
    }
}

// ---------------------------------------------------------------------------
// Segment softmax + aggregation, SINGLE-PASS unnormalized softmax (R4
// structure — best measured). OUTF16: intermediate layers write packed fp16
// activations (read by the next gemm); final layer writes f32.
// ---------------------------------------------------------------------------
template <int H, bool OUTF16>
__global__ __launch_bounds__(128) void gather_kernel(
    const void* __restrict__ hvp, const float* __restrict__ as_,
    const float* __restrict__ ad_, const int* __restrict__ cnt,
    const int* __restrict__ bucket, const int* __restrict__ ovf_src,
    const int* __restrict__ ovf_dst, const int* __restrict__ ovf_cnt,
    const float* __restrict__ bias, void* __restrict__ out, int N) {
    __shared__ int s_src[4][32];
    __shared__ float s_w[4][32 * H];
    int t = threadIdx.x;
    int wv = t >> 6;
    int lane = t & 63;
    int hw = lane >> 5;
    int l = lane & 31;
    int sub = wv * 2 + hw;
    int n = blockIdx.x * 4 + sub;
    if (n >= N) return;

    int deg = cnt[n];
    int totalb = min(deg, CAP) + 1;
    int onum = (deg > CAP) ? *ovf_cnt : 0;
    const int* bk = bucket + (size_t)n * CAP;

    float adv[H];
#pragma unroll
    for (int hh = 0; hh < H; ++hh) adv[hh] = ad_[(size_t)n * H + hh];

    float dsum[H];
#pragma unroll
    for (int hh = 0; hh < H; ++hh) dsum[hh] = 0.f;

    int g = l >> 4;
    int c = l & 15;
    const int head_c = (H == 1) ? 0 : (c >> 2);
    float a8[8];
#pragma unroll
    for (int k = 0; k < 8; ++k) a8[k] = 0.f;
    const uint4* __restrict__ hb4 = (const uint4*)hvp;

    for (int base = 0; base < totalb; base += 32) {
        int cnt2 = min(32, totalb - base);
        if (l < cnt2) {
            int idx = base + l;
            int src = (idx == 0) ? n : bk[idx - 1];
            s_src[sub][l] = src;
            if (H == 4) {
                float4 a4 = ((const float4*)as_)[src];
                float sv4[4] = {a4.x, a4.y, a4.z, a4.w};
#pragma unroll
                for (int hh = 0; hh < 4; ++hh) {
                    float s = sv4[hh] + adv[hh];
                    s = (s > 0.f) ? s : NEG_SLOPE * s;
                    s = fminf(s, 80.f);
                    float p = __expf(s);
                    s_w[sub][l * 4 + hh] = p;
                    dsum[hh] += p;
                }
            } else {
                float s = as_[src] + adv[0];
                s = (s > 0.f) ? s : NEG_SLOPE * s;
                s = fminf(s, 80.f);
                float p = __expf(s);
                s_w[sub][l] = p;
                dsum[0] += p;
            }
        }
        __builtin_amdgcn_wave_barrier();
        int j = 0;
        for (; j + 8 <= cnt2; j += 8) {
            int ts[4];
            float ws[4];
            uint4 rv[4];
#pragma unroll
            for (int u = 0; u < 4; ++u) {
                int e = j + 2 * u + g;
                ts[u] = s_src[sub][e];
                ws[u] = s_w[sub][e * H + head_c];
            }
#pragma unroll
            for (int u = 0; u < 4; ++u) rv[u] = hb4[(size_t)ts[u] * 16 + c];
#pragma unroll
            for (int u = 0; u < 4; ++u) {
                a8[0] += ws[u] * f16_lo(rv[u].x);
                a8[1] += ws[u] * f16_hi(rv[u].x);
                a8[2] += ws[u] * f16_lo(rv[u].y);
                a8[3] += ws[u] * f16_hi(rv[u].y);
                a8[4] += ws[u] * f16_lo(rv[u].z);
                a8[5] += ws[u] * f16_hi(rv[u].z);
                a8[6] += ws[u] * f16_lo(rv[u].w);
                a8[7] += ws[u] * f16_hi(rv[u].w);
            }
        }
        for (; j < cnt2; j += 2) {
            int e = j + g;
            if (e < cnt2) {
                int sj = s_src[sub][e];
                float wj = s_w[sub][e * H + head_c];
                uint4 rv = hb4[(size_t)sj * 16 + c];
                a8[0] += wj * f16_lo(rv.x);
                a8[1] += wj * f16_hi(rv.x);
                a8[2] += wj * f16_lo(rv.y);
                a8[3] += wj * f16_hi(rv.y);
                a8[4] += wj * f16_lo(rv.z);
                a8[5] += wj * f16_hi(rv.z);
                a8[6] += wj * f16_lo(rv.w);
                a8[7] += wj * f16_hi(rv.w);
            }
        }
        __builtin_amdgcn_wave_barrier();
    }

#pragma unroll
    for (int o = 16; o > 0; o >>= 1)
#pragma unroll
        for (int hh = 0; hh < H; ++hh) dsum[hh] += __shfl_xor(dsum[hh], o);

    // overflow edges (deg > CAP): exact, rare; dsum stays lane-uniform
    for (int e = 0; e < onum; ++e) {
        if (ovf_dst[e] == n) {
            int src = ovf_src[e];
            float pv[H];
            if (H == 4) {
                float4 a4 = ((const float4*)as_)[src];
                float sv4[4] = {a4.x, a4.y, a4.z, a4.w};
#pragma unroll
                for (int hh = 0; hh < 4; ++hh) {
                    float s = sv4[hh] + adv[hh];
                    s = (s > 0.f) ? s : NEG_SLOPE * s;
                    s = fminf(s, 80.f);
                    pv[hh] = __expf(s);
                    dsum[hh] += pv[hh];
                }
            } else {
                float s = as_[src] + adv[0];
                s = (s > 0.f) ? s : NEG_SLOPE * s;
                s = fminf(s, 80.f);
                pv[0] = __expf(s);
                dsum[0] += pv[0];
            }
            if (g == 0) {
                float wj = pv[head_c];
                uint4 rv = hb4[(size_t)src * 16 + c];
                a8[0] += wj * f16_lo(rv.x);
                a8[1] += wj * f16_hi(rv.x);
                a8[2] += wj * f16_lo(rv.y);
                a8[3] += wj * f16_hi(rv.y);
                a8[4] += wj * f16_lo(rv.z);
                a8[5] += wj * f16_hi(rv.z);
                a8[6] += wj * f16_lo(rv.w);
                a8[7] += wj * f16_hi(rv.w);
            }
        }
    }

#pragma unroll
    for (int k = 0; k < 8; ++k) a8[k] += __shfl_xor(a8[k], 16);
    if (g == 0) {
        float invc = 1.f / dsum[head_c];
        float v[8];
#pragma unroll
        for (int k = 0; k < 8; ++k)
            v[k] = fmaxf(a8[k] * invc + bias[c * 8 + k], 0.f);
        if (OUTF16) {
            uint4 o16;
            o16.x = f16_pack(v[0], v[1]);
            o16.y = f16_pack(v[2], v[3]);
            o16.z = f16_pack(v[4], v[5]);
            o16.w = f16_pack(v[6], v[7]);
            ((uint4*)out)[(size_t)n * 16 + c] = o16;
        } else {
            float4 o0 = make_float4(v[0], v[1], v[2], v[3]);
            float4 o1 = make_float4(v[4], v[5], v[6], v[7]);
            ((float4*)out)[(size_t)n * 32 + c * 2] = o0;
            ((float4*)out)[(size_t)n * 32 + c * 2 + 1] = o1;
        }
    }
}

// ---------------------------------------------------------------------------
extern "C" void kernel_launch(void* const* d_in, const int* in_sizes, int n_in,
                              void* d_out, int out_size, void* d_ws,
                              size_t ws_size, hipStream_t stream) {
    const float* x   = (const float*)d_in[0];
    const void*  ei  = d_in[1];
    const float* W0  = (const float*)d_in[2];
    const float* as0 = (const float*)d_in[3];
    const float* ad0 = (const float*)d_in[4];
    const float* b0  = (const float*)d_in[5];
    const float* W1  = (const float*)d_in[6];
    const float* as1 = (const float*)d_in[7];
    const float* ad1 = (const float*)d_in[8];
    const float* b1  = (const float*)d_in[9];
    const float* W2  = (const float*)d_in[10];
    const float* as2 = (const float*)d_in[11];
    const float* ad2 = (const float*)d_in[12];
    const float* b2  = (const float*)d_in[13];

    int N = in_sizes[0] / 128;
    int E = in_sizes[1] / 2;
    float* out = (float*)d_out;

    float* h       = (float*)d_ws;                       // N*128 f32-sized (used as fp16)
    int2* nextsrc  = (int2*)(h + (size_t)N * 128);       // E int2
    float* alpha_s = (float*)(nextsrc + E);              // N*4 (max H)
    float* alpha_d = alpha_s + (size_t)N * 4;            // N*4
    int*   cnt     = (int*)(alpha_d + (size_t)N * 4);    // N
    int*   head    = cnt + N;                            // N
    int*   ovf_c   = head + N;                           // 1
    int*   bucket  = ovf_c + 1;                          // N*CAP
    int*   ovf_src = bucket + (size_t)N * CAP;           // E
    int*   ovf_dst = ovf_src + E;                        // E
    unsigned short* wf = (unsigned short*)(ovf_dst + E); // 3*32768 ushort
    unsigned short* act16 = wf + 3 * 32768;              // N*128 fp16 activations

    int eb = (E + 255) / 256;
    int nb = (N + 1 + 255) / 256;
    int gb = (N + 63) / 64;
    int wb = (N + 3) / 4;

    prep_kernel<<<24 + nb, 256, 0, stream>>>(W0, W1, W2, wf, head, ovf_c, N);
    build_kernel<<<eb, 256, 0, stream>>>(ei, E, head, nextsrc);
    convert_kernel<<<nb, 256, 0, stream>>>(head, nextsrc, cnt, bucket,
                                           ovf_src, ovf_dst, ovf_c, N);

    // layer 0: f32 x in, fp16 act out
    gemm_kernel<4, false><<<gb, 256, 0, stream>>>(x, wf, wf + 16384, as0, ad0,
                                                  h, alpha_s, alpha_d, N);
    gather_kernel<4, true><<<wb, 128, 0, stream>>>(h, alpha_s, alpha_d, cnt,
                                                   bucket, ovf_src, ovf_dst,
                                                   ovf_c, b0, act16, N);

    // layer 1: fp16 act in/out
    gemm_kernel<4, true><<<gb, 256, 0, stream>>>(act16, wf + 32768, wf + 49152,
                                                 as1, ad1, h, alpha_s, alpha_d, N);
    gather_kernel<4, true><<<wb, 128, 0, stream>>>(h, alpha_s, alpha_d, cnt,
                                                   bucket, ovf_src, ovf_dst,
                                                   ovf_c, b1, act16, N);

    // layer 2 (H=1): fp16 act in, f32 final out
    gemm_kernel<1, true><<<gb, 256, 0, stream>>>(act16, wf + 65536, wf + 81920,
                                                 as2, ad2, h, alpha_s, alpha_d, N);
    gather_kernel<1, false><<<wb, 128, 0, stream>>>(h, alpha_s, alpha_d, cnt,
                                                    bucket, ovf_src, ovf_dst,
                                                    ovf_c, b2, out, N);
}